// Round 2
// baseline (837.822 us; speedup 1.0000x reference)
//
#include <hip/hip_runtime.h>

typedef unsigned short u16;
typedef __attribute__((ext_vector_type(8))) __bf16 bf16x8;
typedef __attribute__((ext_vector_type(4))) float f32x4;

__device__ __forceinline__ u16 f2bf(float f) {
    unsigned int u = __builtin_bit_cast(unsigned int, f);
    u = (u + 0x7fffu + ((u >> 16) & 1u)) >> 16;
    return (u16)u;
}

typedef __attribute__((address_space(1))) const void gv_t;
typedef __attribute__((address_space(3))) void lv_t;
__device__ __forceinline__ void gl_lds16(const void* g, void* l) {
    __builtin_amdgcn_global_load_lds((gv_t*)g, (lv_t*)l, 16, 0, 0);
}

// ---------------- convert fp32 -> bf16 (vectorized x4) ----------------
__global__ __launch_bounds__(256) void cvt_bf16_k(const float* __restrict__ in,
                                                  u16* __restrict__ out, int n4) {
    int i = blockIdx.x * 256 + threadIdx.x;
    if (i >= n4) return;
    float4 f = ((const float4*)in)[i];
    ushort4 o;
    o.x = f2bf(f.x); o.y = f2bf(f.y); o.z = f2bf(f.z); o.w = f2bf(f.w);
    ((ushort4*)out)[i] = o;
}

// ---- pack attn W [3,16,1024,64] fp32 -> 3 matrices Wt [N=1024][K=1024] bf16 ----
__global__ __launch_bounds__(256) void pack_attn_w_k(const float* __restrict__ W,
                                                     u16* __restrict__ out) {
    int idx = blockIdx.x * 256 + threadIdx.x;     // < 3*16*1024*64 = 3145728
    int kk = idx & 63;
    int d  = (idx >> 6) & 1023;
    int h  = (idx >> 16) & 15;
    int p  = idx >> 20;
    out[p * 1048576 + (h * 64 + kk) * 1024 + d] = f2bf(W[idx]);
}

// ---- transpose fp32 [R][C] -> bf16 [C][R] ----
__global__ __launch_bounds__(256) void transpose_bf16_k(const float* __restrict__ in,
                                                        u16* __restrict__ out, int R, int C) {
    int idx = blockIdx.x * 256 + threadIdx.x;
    if (idx >= R * C) return;
    int r = idx / C, c = idx - r * C;
    out[c * R + r] = f2bf(in[idx]);
}

// ---------------- GEMM: C = A[M,K] @ Bt[N,K]^T + bias, opt relu ----------------
// 128x128 tile, BK=32, 4 waves (2x2), mfma_f32_16x16x32_bf16
template <int RELU, int OUTF32>
__global__ __launch_bounds__(256) void gemm_bt_k(const u16* __restrict__ A,
                                                 const u16* __restrict__ Bt,
                                                 const float* __restrict__ bias,
                                                 u16* __restrict__ Obf,
                                                 float* __restrict__ Of,
                                                 int M, int N, int K) {
    __shared__ u16 As[128 * 32];
    __shared__ u16 Bs[128 * 32];
    const int tid = threadIdx.x, lane = tid & 63, w = tid >> 6;
    const int wr = w >> 1, wc = w & 1;
    const int m0 = blockIdx.y * 128, n0 = blockIdx.x * 128;
    const int rowA = lane >> 2;            // 0..15 within 16-row segment
    const int colk = (lane & 3) * 8;       // 4 chunks of 8 bf16

    f32x4 acc[4][4] = {};

    for (int k0 = 0; k0 < K; k0 += 32) {
        for (int q = 0; q < 2; ++q) {
            int seg = w * 2 + q;           // 0..7, 16 rows each
            gl_lds16(A  + (size_t)(m0 + seg * 16 + rowA) * K + k0 + colk, &As[seg * 512]);
            gl_lds16(Bt + (size_t)(n0 + seg * 16 + rowA) * K + k0 + colk, &Bs[seg * 512]);
        }
        __syncthreads();
        bf16x8 a[4], b[4];
        #pragma unroll
        for (int m = 0; m < 4; ++m)
            a[m] = *(const bf16x8*)&As[(wr * 64 + m * 16 + (lane & 15)) * 32 + (lane >> 4) * 8];
        #pragma unroll
        for (int n = 0; n < 4; ++n)
            b[n] = *(const bf16x8*)&Bs[(wc * 64 + n * 16 + (lane & 15)) * 32 + (lane >> 4) * 8];
        #pragma unroll
        for (int m = 0; m < 4; ++m)
            #pragma unroll
            for (int n = 0; n < 4; ++n)
                acc[m][n] = __builtin_amdgcn_mfma_f32_16x16x32_bf16(a[m], b[n], acc[m][n], 0, 0, 0);
        __syncthreads();
    }

    #pragma unroll
    for (int m = 0; m < 4; ++m)
        #pragma unroll
        for (int n = 0; n < 4; ++n) {
            int col = n0 + wc * 64 + n * 16 + (lane & 15);
            float bv = bias[col];
            #pragma unroll
            for (int i = 0; i < 4; ++i) {
                int row = m0 + wr * 64 + m * 16 + (lane >> 4) * 4 + i;
                float v = acc[m][n][i] + bv;
                if (RELU) v = fmaxf(v, 0.f);
                if (OUTF32) Of[(size_t)row * N + col] = v;
                else        Obf[(size_t)row * N + col] = f2bf(v);
            }
        }
}

// ---------------- flash attention ----------------
// Q,K,V,O layout: [B, S, H*DH] bf16, head offset h*64. One block = 64 q-rows of one (b,h).
// 4 waves x 16 q-rows. KBLK=64. LDS rows padded to 72 elements (144B) to break conflicts.
template <int CAUSAL>
__global__ __launch_bounds__(256) void attn_k(const u16* __restrict__ Q,
                                              const u16* __restrict__ Kg_,
                                              const u16* __restrict__ Vg_,
                                              u16* __restrict__ O, int S) {
    const int HD = 1024;
    __shared__ u16 Kl[64 * 72];
    __shared__ u16 Vt[64 * 72];      // transposed: [dh][sk]
    __shared__ u16 Pl[4 * 16 * 72];  // per-wave P tile [16 q][64 k]
    const int tid = threadIdx.x, lane = tid & 63, w = tid >> 6;
    const int qt = blockIdx.x, h = blockIdx.y, b = blockIdx.z;
    const size_t base = ((size_t)b * S) * HD + h * 64;
    const u16* Qg = Q   + base;
    const u16* Kgp = Kg_ + base;
    const u16* Vgp = Vg_ + base;
    const int q0 = qt * 64 + w * 16;

    bf16x8 aq[2];
    #pragma unroll
    for (int kc = 0; kc < 2; ++kc)
        aq[kc] = *(const bf16x8*)&Qg[(size_t)(q0 + (lane & 15)) * HD + kc * 32 + (lane >> 4) * 8];

    f32x4 acc_o[4] = {};
    float mrow[4], lrow[4];
    #pragma unroll
    for (int i = 0; i < 4; ++i) { mrow[i] = -3.0e38f; lrow[i] = 0.f; }
    u16* Pw = &Pl[w * 16 * 72];

    const int nkb = CAUSAL ? (qt + 1) : (S / 64);
    for (int kb = 0; kb < nkb; ++kb) {
        const int k0 = kb * 64;
        __syncthreads();
        #pragma unroll
        for (int it = 0; it < 2; ++it) {
            int idx = it * 256 + tid;          // 0..511
            int row = idx >> 3, c8 = (idx & 7) * 8;
            *(uint4*)&Kl[row * 72 + c8] = *(const uint4*)&Kgp[(size_t)(k0 + row) * HD + c8];
            uint4 vv = *(const uint4*)&Vgp[(size_t)(k0 + row) * HD + c8];
            const u16* pv = (const u16*)&vv;
            #pragma unroll
            for (int j = 0; j < 8; ++j) Vt[(c8 + j) * 72 + row] = pv[j];
        }
        __syncthreads();

        // QK^T -> scores [16 q][64 k] per wave
        f32x4 accs[4] = {};
        #pragma unroll
        for (int ct = 0; ct < 4; ++ct)
            #pragma unroll
            for (int kc = 0; kc < 2; ++kc) {
                bf16x8 bk = *(const bf16x8*)&Kl[(ct * 16 + (lane & 15)) * 72 + kc * 32 + (lane >> 4) * 8];
                accs[ct] = __builtin_amdgcn_mfma_f32_16x16x32_bf16(aq[kc], bk, accs[ct], 0, 0, 0);
            }

        float vals[4][4], tmax[4];
        #pragma unroll
        for (int i = 0; i < 4; ++i) tmax[i] = -3.0e38f;
        #pragma unroll
        for (int ct = 0; ct < 4; ++ct)
            #pragma unroll
            for (int i = 0; i < 4; ++i) {
                float v = accs[ct][i] * 0.125f;
                if (CAUSAL) {
                    int kg = k0 + ct * 16 + (lane & 15);
                    int qg = q0 + (lane >> 4) * 4 + i;
                    if (kg > qg) v += -1e9f;
                }
                vals[ct][i] = v;
                tmax[i] = fmaxf(tmax[i], v);
            }
        #pragma unroll
        for (int off = 1; off < 16; off <<= 1)
            #pragma unroll
            for (int i = 0; i < 4; ++i) tmax[i] = fmaxf(tmax[i], __shfl_xor(tmax[i], off));

        float scale[4], rsum[4];
        #pragma unroll
        for (int i = 0; i < 4; ++i) {
            float mn = fmaxf(mrow[i], tmax[i]);
            scale[i] = __expf(mrow[i] - mn);
            mrow[i] = mn;
            rsum[i] = 0.f;
        }
        #pragma unroll
        for (int ct = 0; ct < 4; ++ct)
            #pragma unroll
            for (int i = 0; i < 4; ++i) {
                float p = __expf(vals[ct][i] - mrow[i]);
                vals[ct][i] = p;
                rsum[i] += p;
            }
        #pragma unroll
        for (int off = 1; off < 16; off <<= 1)
            #pragma unroll
            for (int i = 0; i < 4; ++i) rsum[i] += __shfl_xor(rsum[i], off);
        #pragma unroll
        for (int i = 0; i < 4; ++i) lrow[i] = lrow[i] * scale[i] + rsum[i];
        #pragma unroll
        for (int dt = 0; dt < 4; ++dt)
            #pragma unroll
            for (int i = 0; i < 4; ++i) acc_o[dt][i] *= scale[i];

        // P -> LDS (bf16), then PV
        #pragma unroll
        for (int ct = 0; ct < 4; ++ct)
            #pragma unroll
            for (int i = 0; i < 4; ++i)
                Pw[((lane >> 4) * 4 + i) * 72 + ct * 16 + (lane & 15)] = f2bf(vals[ct][i]);

        #pragma unroll
        for (int kc2 = 0; kc2 < 2; ++kc2) {
            bf16x8 pa = *(const bf16x8*)&Pw[(lane & 15) * 72 + kc2 * 32 + (lane >> 4) * 8];
            #pragma unroll
            for (int dt = 0; dt < 4; ++dt) {
                bf16x8 bv = *(const bf16x8*)&Vt[(dt * 16 + (lane & 15)) * 72 + kc2 * 32 + (lane >> 4) * 8];
                acc_o[dt] = __builtin_amdgcn_mfma_f32_16x16x32_bf16(pa, bv, acc_o[dt], 0, 0, 0);
            }
        }
    }

    #pragma unroll
    for (int dt = 0; dt < 4; ++dt)
        #pragma unroll
        for (int i = 0; i < 4; ++i) {
            float o = acc_o[dt][i] / lrow[i];
            O[(size_t)(b * S + q0 + (lane >> 4) * 4 + i) * HD + h * 64 + dt * 16 + (lane & 15)] = f2bf(o);
        }
}

extern "C" void kernel_launch(void* const* d_in, const int* in_sizes, int n_in,
                              void* d_out, int out_size, void* d_ws, size_t ws_size,
                              hipStream_t stream) {
    const float* de_x = (const float*)d_in[0];
    const float* en_x = (const float*)d_in[1];
    const float* a1w  = (const float*)d_in[3];
    const float* a1b  = (const float*)d_in[4];
    const float* a2w  = (const float*)d_in[5];
    const float* a2b  = (const float*)d_in[6];
    const float* fw1  = (const float*)d_in[7];
    const float* fb1  = (const float*)d_in[8];
    const float* fw2  = (const float*)d_in[9];
    const float* fb2  = (const float*)d_in[10];
    float* out = (float*)d_out;
    u16* ws = (u16*)d_ws;

    // workspace layout (elements of u16); mid aliases Qb/Kb (dead by FFN time)
    u16* bf_de = ws + 0;          // 8192*1024
    u16* bf_en = ws + 8388608;    // 8192*1024
    u16* w1    = ws + 16777216;   // 3 x 1024*1024 (q,k,v)
    u16* w2    = ws + 19922944;   // 3 x 1024*1024
    u16* wf1t  = ws + 23068672;   // [2048][1024]
    u16* wf2t  = ws + 25165824;   // [1024][2048]
    u16* Qb    = ws + 27262976;   // 8192*1024
    u16* Kb    = ws + 35651584;
    u16* Vb    = ws + 44040192;
    u16* h1    = ws + 52428800;
    u16* h2    = ws + 60817408;
    u16* mid   = ws + 27262976;   // 8192*2048, aliases Qb+Kb (dead after attn2)
    if (ws_size < (size_t)69206016 * 2) return;  // 138.4 MB

    const int M = 8192;
    dim3 blk(256);

    cvt_bf16_k<<<8192, blk, 0, stream>>>(de_x, bf_de, 2097152);
    cvt_bf16_k<<<8192, blk, 0, stream>>>(en_x, bf_en, 2097152);
    pack_attn_w_k<<<12288, blk, 0, stream>>>(a1w, w1);
    pack_attn_w_k<<<12288, blk, 0, stream>>>(a2w, w2);
    transpose_bf16_k<<<8192, blk, 0, stream>>>(fw1, wf1t, 1024, 2048);
    transpose_bf16_k<<<8192, blk, 0, stream>>>(fw2, wf2t, 2048, 1024);

    dim3 gp(8, 64);
    // block 1: Q from de_x, K/V from en_x, causal
    gemm_bt_k<0, 0><<<gp, blk, 0, stream>>>(bf_de, w1 + 0,       a1b + 0,    Qb, nullptr, M, 1024, 1024);
    gemm_bt_k<0, 0><<<gp, blk, 0, stream>>>(bf_en, w1 + 1048576, a1b + 1024, Kb, nullptr, M, 1024, 1024);
    gemm_bt_k<0, 0><<<gp, blk, 0, stream>>>(bf_en, w1 + 2097152, a1b + 2048, Vb, nullptr, M, 1024, 1024);
    attn_k<1><<<dim3(16, 16, 8), blk, 0, stream>>>(Qb, Kb, Vb, h1, 1024);

    // block 2: Q from h1, K/V from en_x, no mask
    gemm_bt_k<0, 0><<<gp, blk, 0, stream>>>(h1,    w2 + 0,       a2b + 0,    Qb, nullptr, M, 1024, 1024);
    gemm_bt_k<0, 0><<<gp, blk, 0, stream>>>(bf_en, w2 + 1048576, a2b + 1024, Kb, nullptr, M, 1024, 1024);
    gemm_bt_k<0, 0><<<gp, blk, 0, stream>>>(bf_en, w2 + 2097152, a2b + 2048, Vb, nullptr, M, 1024, 1024);
    attn_k<0><<<dim3(16, 16, 8), blk, 0, stream>>>(Qb, Kb, Vb, h2, 1024);

    // FFN
    gemm_bt_k<1, 0><<<dim3(16, 64), blk, 0, stream>>>(h2,  wf1t, fb1, mid, nullptr, M, 2048, 1024);
    gemm_bt_k<0, 1><<<gp, blk, 0, stream>>>(mid, wf2t, fb2, nullptr, out, M, 1024, 2048);
}

// Round 3
// 711.902 us; speedup vs baseline: 1.1769x; 1.1769x over previous
//
#include <hip/hip_runtime.h>

typedef unsigned short u16;
typedef __attribute__((ext_vector_type(8))) __bf16 bf16x8;
typedef __attribute__((ext_vector_type(4))) float f32x4;

__device__ __forceinline__ u16 f2bf(float f) {
    unsigned int u = __builtin_bit_cast(unsigned int, f);
    u = (u + 0x7fffu + ((u >> 16) & 1u)) >> 16;
    return (u16)u;
}

typedef __attribute__((address_space(1))) const void gv_t;
typedef __attribute__((address_space(3))) void lv_t;
__device__ __forceinline__ void gl_lds16(const void* g, void* l) {
    __builtin_amdgcn_global_load_lds((gv_t*)g, (lv_t*)l, 16, 0, 0);
}

// ---------------- convert fp32 -> bf16 (vectorized x4) ----------------
__global__ __launch_bounds__(256) void cvt_bf16_k(const float* __restrict__ in,
                                                  u16* __restrict__ out, int n4) {
    int i = blockIdx.x * 256 + threadIdx.x;
    if (i >= n4) return;
    float4 f = ((const float4*)in)[i];
    ushort4 o;
    o.x = f2bf(f.x); o.y = f2bf(f.y); o.z = f2bf(f.z); o.w = f2bf(f.w);
    ((ushort4*)out)[i] = o;
}

// ---- pack attn W [3,16,1024,64] fp32 -> 3 matrices Wt [N=1024][K=1024] bf16 ----
__global__ __launch_bounds__(256) void pack_attn_w_k(const float* __restrict__ W,
                                                     u16* __restrict__ out) {
    int idx = blockIdx.x * 256 + threadIdx.x;     // < 3*16*1024*64 = 3145728
    int kk = idx & 63;
    int d  = (idx >> 6) & 1023;
    int h  = (idx >> 16) & 15;
    int p  = idx >> 20;
    out[p * 1048576 + (h * 64 + kk) * 1024 + d] = f2bf(W[idx]);
}

// ---- transpose fp32 [R][C] -> bf16 [C][R] ----
__global__ __launch_bounds__(256) void transpose_bf16_k(const float* __restrict__ in,
                                                        u16* __restrict__ out, int R, int C) {
    int idx = blockIdx.x * 256 + threadIdx.x;
    if (idx >= R * C) return;
    int r = idx / C, c = idx - r * C;
    out[c * R + r] = f2bf(in[idx]);
}

// ---------------- GEMM: C = (A[M,K] @ Bt[N,K]^T + bias) [relu] * scale ----------------
// 128x128 tile, BK=32, 4 waves (2x2), mfma_f32_16x16x32_bf16
template <int RELU, int OUTF32>
__global__ __launch_bounds__(256) void gemm_bt_k(const u16* __restrict__ A,
                                                 const u16* __restrict__ Bt,
                                                 const float* __restrict__ bias,
                                                 u16* __restrict__ Obf,
                                                 float* __restrict__ Of,
                                                 int M, int N, int K, float scale) {
    __shared__ u16 As[128 * 32];
    __shared__ u16 Bs[128 * 32];
    const int tid = threadIdx.x, lane = tid & 63, w = tid >> 6;
    const int wr = w >> 1, wc = w & 1;
    const int m0 = blockIdx.y * 128, n0 = blockIdx.x * 128;
    const int rowA = lane >> 2;
    const int colk = (lane & 3) * 8;

    f32x4 acc[4][4] = {};

    for (int k0 = 0; k0 < K; k0 += 32) {
        for (int q = 0; q < 2; ++q) {
            int seg = w * 2 + q;
            gl_lds16(A  + (size_t)(m0 + seg * 16 + rowA) * K + k0 + colk, &As[seg * 512]);
            gl_lds16(Bt + (size_t)(n0 + seg * 16 + rowA) * K + k0 + colk, &Bs[seg * 512]);
        }
        __syncthreads();
        bf16x8 a[4], b[4];
        #pragma unroll
        for (int m = 0; m < 4; ++m)
            a[m] = *(const bf16x8*)&As[(wr * 64 + m * 16 + (lane & 15)) * 32 + (lane >> 4) * 8];
        #pragma unroll
        for (int n = 0; n < 4; ++n)
            b[n] = *(const bf16x8*)&Bs[(wc * 64 + n * 16 + (lane & 15)) * 32 + (lane >> 4) * 8];
        #pragma unroll
        for (int m = 0; m < 4; ++m)
            #pragma unroll
            for (int n = 0; n < 4; ++n)
                acc[m][n] = __builtin_amdgcn_mfma_f32_16x16x32_bf16(a[m], b[n], acc[m][n], 0, 0, 0);
        __syncthreads();
    }

    #pragma unroll
    for (int m = 0; m < 4; ++m)
        #pragma unroll
        for (int n = 0; n < 4; ++n) {
            int col = n0 + wc * 64 + n * 16 + (lane & 15);
            float bv = bias[col];
            #pragma unroll
            for (int i = 0; i < 4; ++i) {
                int row = m0 + wr * 64 + m * 16 + (lane >> 4) * 4 + i;
                float v = acc[m][n][i] + bv;
                if (RELU) v = fmaxf(v, 0.f);
                v *= scale;
                if (OUTF32) Of[(size_t)row * N + col] = v;
                else        Obf[(size_t)row * N + col] = f2bf(v);
            }
        }
}

// ---------------- fused projection GEMM ----------------
// W rows: [0,1024)=Q1 [1024,2048)=K1 [2048,3072)=V1 [3072,4096)=Q2(skipped)
//         [4096,5120)=K2 [5120,6144)=V2.  A = de_x for Q1, en_x otherwise.
// Q segment scaled by 0.125 (folds 1/sqrt(dh) into Q). V segments written
// TRANSPOSED: Vt[(b*16+h)*64+dh][s].
__global__ __launch_bounds__(256) void gemm_proj_k(const u16* __restrict__ Ade,
                                                   const u16* __restrict__ Aen,
                                                   const u16* __restrict__ W,
                                                   const float* __restrict__ b1,
                                                   const float* __restrict__ b2,
                                                   u16* __restrict__ Qb,
                                                   u16* __restrict__ Kb1, u16* __restrict__ Vt1,
                                                   u16* __restrict__ Kb2, u16* __restrict__ Vt2) {
    const int K = 1024;
    __shared__ u16 As[128 * 32];
    __shared__ u16 Bs[128 * 32];
    const int tid = threadIdx.x, lane = tid & 63, w = tid >> 6;
    const int wr = w >> 1, wc = w & 1;
    const int xt = blockIdx.x;
    const int n0 = (xt < 24 ? xt : xt + 8) * 128;   // skip Q2 segment
    const int seg = n0 >> 10;                        // 0,1,2,4,5
    const int m0 = blockIdx.y * 128;
    const u16* A  = (seg == 0) ? Ade : Aen;
    const u16* Bt = W + (size_t)n0 * K;
    const float* bias = (seg < 3) ? (b1 + seg * 1024) : (b2 + (seg - 3) * 1024);
    const int nb = n0 & 1023;                        // col base within segment
    const int rowA = lane >> 2;
    const int colk = (lane & 3) * 8;

    f32x4 acc[4][4] = {};

    for (int k0 = 0; k0 < K; k0 += 32) {
        for (int q = 0; q < 2; ++q) {
            int sg = w * 2 + q;
            gl_lds16(A  + (size_t)(m0 + sg * 16 + rowA) * K + k0 + colk, &As[sg * 512]);
            gl_lds16(Bt + (size_t)(sg * 16 + rowA) * K + k0 + colk, &Bs[sg * 512]);
        }
        __syncthreads();
        bf16x8 a[4], b[4];
        #pragma unroll
        for (int m = 0; m < 4; ++m)
            a[m] = *(const bf16x8*)&As[(wr * 64 + m * 16 + (lane & 15)) * 32 + (lane >> 4) * 8];
        #pragma unroll
        for (int n = 0; n < 4; ++n)
            b[n] = *(const bf16x8*)&Bs[(wc * 64 + n * 16 + (lane & 15)) * 32 + (lane >> 4) * 8];
        #pragma unroll
        for (int m = 0; m < 4; ++m)
            #pragma unroll
            for (int n = 0; n < 4; ++n)
                acc[m][n] = __builtin_amdgcn_mfma_f32_16x16x32_bf16(a[m], b[n], acc[m][n], 0, 0, 0);
        __syncthreads();
    }

    const int isV = (seg == 2 || seg == 5);
    u16* Orow = (seg == 0) ? Qb : (seg == 1 ? Kb1 : Kb2);
    u16* Ovt  = (seg == 2) ? Vt1 : Vt2;
    const float scale = (seg == 0) ? 0.125f : 1.0f;

    #pragma unroll
    for (int m = 0; m < 4; ++m)
        #pragma unroll
        for (int n = 0; n < 4; ++n) {
            int col = nb + wc * 64 + n * 16 + (lane & 15);   // 0..1023 within segment
            float bv = bias[col];
            int row0 = m0 + wr * 64 + m * 16 + (lane >> 4) * 4;
            if (isV) {
                ushort4 o;
                o.x = f2bf(acc[m][n][0] + bv);
                o.y = f2bf(acc[m][n][1] + bv);
                o.z = f2bf(acc[m][n][2] + bv);
                o.w = f2bf(acc[m][n][3] + bv);
                // Vt[(b*16 + h)*64 + dh][s]
                size_t off = ((size_t)((row0 >> 10) * 16 + (col >> 6)) * 64 + (col & 63)) * 1024
                             + (row0 & 1023);
                *(ushort4*)&Ovt[off] = o;
            } else {
                #pragma unroll
                for (int i = 0; i < 4; ++i) {
                    float v = (acc[m][n][i] + bv) * scale;
                    Orow[(size_t)(row0 + i) * 1024 + col] = f2bf(v);
                }
            }
        }
}

// ---------------- flash attention ----------------
// Q: [B,S,HD] bf16 pre-scaled by 1/8. K: [B,S,HD]. Vt: [(b*16+h)*64+dh][S].
// One block = 64 q-rows of one (b,h); 4 waves x 16 q-rows; KBLK=64.
// K/Vt tiles: 64 rows x 64 cols (128B rows), XOR chunk swizzle (chunk ^= row&7),
// staged via global_load_lds (linear dest, pre-swizzled global source),
// double-buffered (2-phase pipeline).
template <int CAUSAL>
__global__ __launch_bounds__(256) void attn_k(const u16* __restrict__ Q,
                                              const u16* __restrict__ Kg_,
                                              const u16* __restrict__ Vt_,
                                              u16* __restrict__ O, int S) {
    const int HD = 1024;
    __shared__ u16 Kl[2][4096];
    __shared__ u16 Vl[2][4096];
    __shared__ u16 Pl[4][16 * 72];
    const int tid = threadIdx.x, lane = tid & 63, w = tid >> 6;
    const int qt = blockIdx.x, h = blockIdx.y, b = blockIdx.z;
    const u16* Qg  = Q   + ((size_t)b * S) * HD + h * 64;
    const u16* Kgp = Kg_ + ((size_t)b * S) * HD + h * 64;
    const u16* Vtp = Vt_ + (size_t)(b * 16 + h) * 64 * 1024;
    const int q0 = qt * 64 + w * 16;
    const int l15 = lane & 15, l4 = lane >> 4;
    const int sr = lane >> 3, sc = lane & 7;   // staging row-in-8 / chunk

    bf16x8 aq[2];
    #pragma unroll
    for (int kc = 0; kc < 2; ++kc)
        aq[kc] = *(const bf16x8*)&Qg[(size_t)(q0 + l15) * HD + kc * 32 + l4 * 8];

    f32x4 acc_o[4] = {};
    float mrow[4], lrow[4];
    #pragma unroll
    for (int i = 0; i < 4; ++i) { mrow[i] = -3.0e38f; lrow[i] = 0.f; }
    u16* Pw = Pl[w];

    const int nkb = CAUSAL ? (qt + 1) : (S / 64);

    // prologue stage tile 0 into buf 0
    {
        const int k0 = 0;
        #pragma unroll
        for (int qq = 0; qq < 2; ++qq) {
            int rbase = w * 16 + qq * 8;
            int r = rbase + sr;
            int cs = sc ^ (r & 7);
            gl_lds16(Kgp + (size_t)(k0 + r) * HD + cs * 8, (void*)&Kl[0][rbase * 64]);
            gl_lds16(Vtp + (size_t)r * 1024 + k0 + cs * 8, (void*)&Vl[0][rbase * 64]);
        }
    }
    __syncthreads();

    int buf = 0;
    for (int kb = 0; kb < nkb; ++kb) {
        if (kb + 1 < nkb) {
            const int k0n = (kb + 1) * 64;
            #pragma unroll
            for (int qq = 0; qq < 2; ++qq) {
                int rbase = w * 16 + qq * 8;
                int r = rbase + sr;
                int cs = sc ^ (r & 7);
                gl_lds16(Kgp + (size_t)(k0n + r) * HD + cs * 8, (void*)&Kl[buf ^ 1][rbase * 64]);
                gl_lds16(Vtp + (size_t)r * 1024 + k0n + cs * 8, (void*)&Vl[buf ^ 1][rbase * 64]);
            }
        }
        const u16* Kc = Kl[buf];
        const u16* Vc = Vl[buf];

        // QK^T: scores [16 q][64 k] per wave (Q pre-scaled)
        f32x4 accs[4] = {};
        #pragma unroll
        for (int ct = 0; ct < 4; ++ct) {
            int row = ct * 16 + l15;
            #pragma unroll
            for (int kc = 0; kc < 2; ++kc) {
                int g = kc * 4 + l4;
                bf16x8 bk = *(const bf16x8*)&Kc[row * 64 + (g ^ (row & 7)) * 8];
                accs[ct] = __builtin_amdgcn_mfma_f32_16x16x32_bf16(aq[kc], bk, accs[ct], 0, 0, 0);
            }
        }

        float vals[4][4], tmax[4];
        #pragma unroll
        for (int i = 0; i < 4; ++i) tmax[i] = -3.0e38f;
        if (CAUSAL && kb == qt) {
            #pragma unroll
            for (int ct = 0; ct < 4; ++ct)
                #pragma unroll
                for (int i = 0; i < 4; ++i) {
                    float v = accs[ct][i];
                    int kr = ct * 16 + l15;          // key rel to tile base (= qt*64)
                    int qr = w * 16 + l4 * 4 + i;    // query rel to qt*64
                    if (kr > qr) v = -1.0e9f;
                    vals[ct][i] = v;
                    tmax[i] = fmaxf(tmax[i], v);
                }
        } else {
            #pragma unroll
            for (int ct = 0; ct < 4; ++ct)
                #pragma unroll
                for (int i = 0; i < 4; ++i) {
                    float v = accs[ct][i];
                    vals[ct][i] = v;
                    tmax[i] = fmaxf(tmax[i], v);
                }
        }
        #pragma unroll
        for (int off = 1; off < 16; off <<= 1)
            #pragma unroll
            for (int i = 0; i < 4; ++i) tmax[i] = fmaxf(tmax[i], __shfl_xor(tmax[i], off));

        float scale[4], rsum[4];
        #pragma unroll
        for (int i = 0; i < 4; ++i) {
            float mn = fmaxf(mrow[i], tmax[i]);
            scale[i] = __expf(mrow[i] - mn);
            mrow[i] = mn;
            rsum[i] = 0.f;
        }
        #pragma unroll
        for (int ct = 0; ct < 4; ++ct)
            #pragma unroll
            for (int i = 0; i < 4; ++i) {
                float p = __expf(vals[ct][i] - mrow[i]);
                vals[ct][i] = p;
                rsum[i] += p;
            }
        #pragma unroll
        for (int off = 1; off < 16; off <<= 1)
            #pragma unroll
            for (int i = 0; i < 4; ++i) rsum[i] += __shfl_xor(rsum[i], off);
        #pragma unroll
        for (int i = 0; i < 4; ++i) lrow[i] = lrow[i] * scale[i] + rsum[i];
        #pragma unroll
        for (int dt = 0; dt < 4; ++dt)
            #pragma unroll
            for (int i = 0; i < 4; ++i) acc_o[dt][i] *= scale[i];

        // P -> LDS (bf16), then PV
        #pragma unroll
        for (int ct = 0; ct < 4; ++ct)
            #pragma unroll
            for (int i = 0; i < 4; ++i)
                Pw[(l4 * 4 + i) * 72 + ct * 16 + l15] = f2bf(vals[ct][i]);

        #pragma unroll
        for (int kc2 = 0; kc2 < 2; ++kc2) {
            bf16x8 pa = *(const bf16x8*)&Pw[l15 * 72 + kc2 * 32 + l4 * 8];
            #pragma unroll
            for (int dt = 0; dt < 4; ++dt) {
                int row = dt * 16 + l15;             // dh
                int g = kc2 * 4 + l4;
                bf16x8 bv = *(const bf16x8*)&Vc[row * 64 + (g ^ (row & 7)) * 8];
                acc_o[dt] = __builtin_amdgcn_mfma_f32_16x16x32_bf16(pa, bv, acc_o[dt], 0, 0, 0);
            }
        }
        __syncthreads();
        buf ^= 1;
    }

    #pragma unroll
    for (int dt = 0; dt < 4; ++dt)
        #pragma unroll
        for (int i = 0; i < 4; ++i) {
            float o = acc_o[dt][i] / lrow[i];
            O[(size_t)(b * S + q0 + l4 * 4 + i) * HD + h * 64 + dt * 16 + l15] = f2bf(o);
        }
}

extern "C" void kernel_launch(void* const* d_in, const int* in_sizes, int n_in,
                              void* d_out, int out_size, void* d_ws, size_t ws_size,
                              hipStream_t stream) {
    const float* de_x = (const float*)d_in[0];
    const float* en_x = (const float*)d_in[1];
    const float* a1w  = (const float*)d_in[3];
    const float* a1b  = (const float*)d_in[4];
    const float* a2w  = (const float*)d_in[5];
    const float* a2b  = (const float*)d_in[6];
    const float* fw1  = (const float*)d_in[7];
    const float* fb1  = (const float*)d_in[8];
    const float* fw2  = (const float*)d_in[9];
    const float* fb2  = (const float*)d_in[10];
    float* out = (float*)d_out;
    u16* ws = (u16*)d_ws;

    // workspace layout (u16 elems), 138.4 MB total with aliases:
    u16* bf_de = ws + 0;          // 8388608   (later: h2)
    u16* bf_en = ws + 8388608;    // 8388608   (later: h1)
    u16* wproj = ws + 16777216;   // 6291456 = 6 x [1024][1024]
    u16* wf1t  = ws + 23068672;   // 2097152
    u16* wf2t  = ws + 25165824;   // 2097152
    u16* Qb    = ws + 27262976;   // 8388608
    u16* Kb1   = ws + 35651584;   // 8388608   (later: mid, spans Kb1+Vt1)
    u16* Vt1   = ws + 44040192;   // 8388608
    u16* Kb2   = ws + 52428800;   // 8388608
    u16* Vt2   = ws + 60817408;   // 8388608
    u16* h1  = bf_en;
    u16* h2  = bf_de;
    u16* mid = Kb1;               // 16777216 elems
    if (ws_size < (size_t)69206016 * 2) return;

    const int M = 8192;
    dim3 blk(256);

    cvt_bf16_k<<<8192, blk, 0, stream>>>(de_x, bf_de, 2097152);
    cvt_bf16_k<<<8192, blk, 0, stream>>>(en_x, bf_en, 2097152);
    pack_attn_w_k<<<12288, blk, 0, stream>>>(a1w, wproj);
    pack_attn_w_k<<<12288, blk, 0, stream>>>(a2w, wproj + 3145728);
    transpose_bf16_k<<<8192, blk, 0, stream>>>(fw1, wf1t, 1024, 2048);
    transpose_bf16_k<<<8192, blk, 0, stream>>>(fw2, wf2t, 2048, 1024);

    // fused projections: Q1,K1,V1,K2,V2 (Q scaled, V transposed)
    gemm_proj_k<<<dim3(40, 64), blk, 0, stream>>>(bf_de, bf_en, wproj, a1b, a2b,
                                                  Qb, Kb1, Vt1, Kb2, Vt2);
    attn_k<1><<<dim3(16, 16, 8), blk, 0, stream>>>(Qb, Kb1, Vt1, h1, 1024);

    // Q2 = h1 @ Wq2 (scaled)
    gemm_bt_k<0, 0><<<dim3(8, 64), blk, 0, stream>>>(h1, wproj + 3145728, a2b,
                                                     Qb, nullptr, M, 1024, 1024, 0.125f);
    attn_k<0><<<dim3(16, 16, 8), blk, 0, stream>>>(Qb, Kb2, Vt2, h2, 1024);

    // FFN
    gemm_bt_k<1, 0><<<dim3(16, 64), blk, 0, stream>>>(h2, wf1t, fb1, mid, nullptr,
                                                      M, 2048, 1024, 1.0f);
    gemm_bt_k<0, 1><<<dim3(8, 64), blk, 0, stream>>>(mid, wf2t, fb2, nullptr, out,
                                                     M, 1024, 2048, 1.0f);
}

// Round 5
// 700.317 us; speedup vs baseline: 1.1963x; 1.0165x over previous
//
#include <hip/hip_runtime.h>

typedef unsigned short u16;
typedef __attribute__((ext_vector_type(8))) __bf16 bf16x8;
typedef __attribute__((ext_vector_type(4))) float f32x4;

__device__ __forceinline__ u16 f2bf(float f) {
    unsigned int u = __builtin_bit_cast(unsigned int, f);
    u = (u + 0x7fffu + ((u >> 16) & 1u)) >> 16;
    return (u16)u;
}

typedef __attribute__((address_space(1))) const void gv_t;
typedef __attribute__((address_space(3))) void lv_t;
__device__ __forceinline__ void gl_lds16(const void* g, void* l) {
    __builtin_amdgcn_global_load_lds((gv_t*)g, (lv_t*)l, 16, 0, 0);
}

// ---------------- convert fp32 -> bf16 (vectorized x4) ----------------
__global__ __launch_bounds__(256) void cvt_bf16_k(const float* __restrict__ in,
                                                  u16* __restrict__ out, int n4) {
    int i = blockIdx.x * 256 + threadIdx.x;
    if (i >= n4) return;
    float4 f = ((const float4*)in)[i];
    ushort4 o;
    o.x = f2bf(f.x); o.y = f2bf(f.y); o.z = f2bf(f.z); o.w = f2bf(f.w);
    ((ushort4*)out)[i] = o;
}

// ---- pack attn W [3,16,1024,64] fp32 -> 3 matrices Wt [N=1024][K=1024] bf16 ----
__global__ __launch_bounds__(256) void pack_attn_w_k(const float* __restrict__ W,
                                                     u16* __restrict__ out) {
    int idx = blockIdx.x * 256 + threadIdx.x;
    int kk = idx & 63;
    int d  = (idx >> 6) & 1023;
    int h  = (idx >> 16) & 15;
    int p  = idx >> 20;
    out[p * 1048576 + (h * 64 + kk) * 1024 + d] = f2bf(W[idx]);
}

// ---- transpose fp32 [R][C] -> bf16 [C][R] ----
__global__ __launch_bounds__(256) void transpose_bf16_k(const float* __restrict__ in,
                                                        u16* __restrict__ out, int R, int C) {
    int idx = blockIdx.x * 256 + threadIdx.x;
    if (idx >= R * C) return;
    int r = idx / C, c = idx - r * C;
    out[c * R + r] = f2bf(in[idx]);
}

// ================= 256x256 8-phase GEMM core (T2+T3+T4+T5) =================
// BM=BN=256, BK=64, 512 threads = 8 waves (2M x 4N). Per-wave C = 128x64.
// LDS: As/Bs each 2 bufs x [256][64] bf16 (32KB/buf, 128KB total, 1 block/CU).
// Swizzle: 16B-granule g ^= (row&7); staged linearly via global_load_lds with
// inverse-swizzled global source (rule #21); ds_read applies the same XOR.
//
// RACE-FREE STAGE SCHEDULE (desk-verified, round-4 fix):
//   region free-windows (from last ds_read + barrier):
//     A-buf0 free after ph2 | B-buf0 after ph3 | A-buf1 after ph6 | B-buf1 after ph7
//   one half-tile staged per phase, only inside its window:
//     ph0:A(t1)h1->b1  ph1:B(t1)h0->b1  ph2:B(t1)h1->b1  ph3:A(t2)h0->b0
//     ph4:A(t2)h1->b0  ph5:B(t2)h0->b0  ph6:B(t2)h1->b0  ph7:A(t3)h0->b1
//   counted waits: vmcnt(2) at ph3-end (tile t1 landed; A(t2)h0 in flight) and
//   ph7-end (tile t2 landed; A(t3)h0 in flight). Ledger: prologue 10->2,
//   steady 10->2, last-iter ph3 6->0. No vmcnt(0) in main loop.
__device__ __forceinline__ void g256_core(const u16* __restrict__ Ab,
                                          const u16* __restrict__ Bb,
                                          int K, u16* __restrict__ As,
                                          u16* __restrict__ Bs,
                                          f32x4 (&acc)[8][4]) {
    const int tid = threadIdx.x, lane = tid & 63, wid = tid >> 6;
    const int wm = wid >> 2, wn = wid & 3;
    const int l15 = lane & 15, l4 = lane >> 4;
    const int gsw = (lane & 7) ^ ((lane >> 3) & 7);  // inverse-swizzled src granule
    const int lr = lane >> 3;

    bf16x8 a[4][2], b[2][2];

#define STG(MATb, MATs, buf, half, kt) { \
    _Pragma("unroll") \
    for (int j = 0; j < 2; ++j) { \
        const int r = (half) * 128 + j * 64 + wid * 8; \
        gl_lds16(MATb + (size_t)(r + lr) * K + (kt) * 64 + gsw * 8, \
                 &MATs[(buf) * 16384 + r * 64]); \
    } }
#define LDA(buf, MLO) { \
    _Pragma("unroll") \
    for (int mf = 0; mf < 4; ++mf) \
    _Pragma("unroll") \
    for (int ks = 0; ks < 2; ++ks) \
        a[mf][ks] = *(const bf16x8*)&As[(buf) * 16384 \
            + (wm * 128 + ((MLO) + mf) * 16 + l15) * 64 \
            + (((ks * 4 + l4) ^ (l15 & 7)) * 8)]; \
    }
#define LDB(buf, NLO) { \
    _Pragma("unroll") \
    for (int nf = 0; nf < 2; ++nf) \
    _Pragma("unroll") \
    for (int ks = 0; ks < 2; ++ks) \
        b[nf][ks] = *(const bf16x8*)&Bs[(buf) * 16384 \
            + (wn * 64 + ((NLO) + nf) * 16 + l15) * 64 \
            + (((ks * 4 + l4) ^ (l15 & 7)) * 8)]; \
    }
#define MMA(MLO, NLO) { \
    __builtin_amdgcn_s_setprio(1); \
    _Pragma("unroll") \
    for (int mf = 0; mf < 4; ++mf) \
    _Pragma("unroll") \
    for (int nf = 0; nf < 2; ++nf) \
    _Pragma("unroll") \
    for (int ks = 0; ks < 2; ++ks) \
        acc[(MLO) + mf][(NLO) + nf] = __builtin_amdgcn_mfma_f32_16x16x32_bf16( \
            a[mf][ks], b[nf][ks], acc[(MLO) + mf][(NLO) + nf], 0, 0, 0); \
    __builtin_amdgcn_s_setprio(0); \
    }
#define BARR __builtin_amdgcn_s_barrier()
#define LGKM0 { asm volatile("s_waitcnt lgkmcnt(0)" ::: "memory"); \
                __builtin_amdgcn_sched_barrier(0); }
#define WTV2 asm volatile("s_waitcnt vmcnt(2)" ::: "memory")
#define WTV0 asm volatile("s_waitcnt vmcnt(0)" ::: "memory")

    const int NI = K >> 7;   // 2 K-tiles (BK=64) per iteration; K % 128 == 0
    // prologue: tile0 (A+B -> buf0) + A(1)h0 -> buf1; retire tile0
    STG(Ab, As, 0, 0, 0); STG(Ab, As, 0, 1, 0);
    STG(Bb, Bs, 0, 0, 0); STG(Bb, Bs, 0, 1, 0);
    STG(Ab, As, 1, 0, 1);
    WTV2;
    BARR;

    for (int it = 0; it < NI; ++it) {
        const int t1 = 2 * it + 1, t2 = 2 * it + 2, t3 = 2 * it + 3;
        const bool nl = (it + 1 < NI);
        // ph0
        LDA(0, 0); LDB(0, 0);
        STG(Ab, As, 1, 1, t1);
        BARR; LGKM0; MMA(0, 0); BARR;
        // ph1
        LDB(0, 2);
        STG(Bb, Bs, 1, 0, t1);
        BARR; LGKM0; MMA(0, 2); BARR;
        // ph2
        LDA(0, 4); LDB(0, 0);
        STG(Bb, Bs, 1, 1, t1);
        BARR; LGKM0; MMA(4, 0); BARR;
        // ph3  (A-buf0 free since ph2 barrier)
        LDB(0, 2);
        if (nl) STG(Ab, As, 0, 0, t2);
        BARR; LGKM0; MMA(4, 2);
        if (nl) { WTV2; } else { WTV0; }   // tile t1 fully landed before ph4 reads
        BARR;
        // ph4
        LDA(1, 0); LDB(1, 0);
        if (nl) STG(Ab, As, 0, 1, t2);
        BARR; LGKM0; MMA(0, 0); BARR;
        // ph5  (B-buf0 free since ph3 barrier)
        LDB(1, 2);
        if (nl) STG(Bb, Bs, 0, 0, t2);
        BARR; LGKM0; MMA(0, 2); BARR;
        // ph6
        LDA(1, 4); LDB(1, 0);
        if (nl) STG(Bb, Bs, 0, 1, t2);
        BARR; LGKM0; MMA(4, 0); BARR;
        // ph7  (A-buf1 free since ph6 barrier)
        LDB(1, 2);
        if (nl) STG(Ab, As, 1, 0, t3);
        BARR; LGKM0; MMA(4, 2);
        if (nl) WTV2;                      // tile t2 fully landed before next ph0
        BARR;
    }
#undef STG
#undef LDA
#undef LDB
#undef MMA
#undef BARR
#undef LGKM0
#undef WTV2
#undef WTV0
}

// ---------------- generic 256x256 GEMM: C = (A @ Bt^T + bias)[relu]*scale ----
// MODE 0: bf16 out (*scale); MODE 1: relu -> bf16; MODE 2: f32 out
template <int MODE>
__global__ __launch_bounds__(512, 2) void gemm256_k(const u16* __restrict__ A,
        const u16* __restrict__ Bt, const float* __restrict__ bias,
        u16* __restrict__ Obf, float* __restrict__ Of,
        int M, int N, int K, float scale) {
    __shared__ u16 As[32768];
    __shared__ u16 Bs[32768];
    const int m0 = blockIdx.y * 256, n0 = blockIdx.x * 256;
    f32x4 acc[8][4] = {};
    g256_core(A + (size_t)m0 * K, Bt + (size_t)n0 * K, K, As, Bs, acc);

    const int lane = threadIdx.x & 63, wid = threadIdx.x >> 6;
    const int wm = wid >> 2, wn = wid & 3, l15 = lane & 15, l4 = lane >> 4;
    #pragma unroll
    for (int mf = 0; mf < 8; ++mf)
        #pragma unroll
        for (int nf = 0; nf < 4; ++nf) {
            int col = n0 + wn * 64 + nf * 16 + l15;
            float bv = bias[col];
            int row0 = m0 + wm * 128 + mf * 16 + l4 * 4;
            #pragma unroll
            for (int i = 0; i < 4; ++i) {
                float v = acc[mf][nf][i] + bv;
                if (MODE == 1) v = fmaxf(v, 0.f);
                v *= scale;
                if (MODE == 2) Of[(size_t)(row0 + i) * N + col] = v;
                else           Obf[(size_t)(row0 + i) * N + col] = f2bf(v);
            }
        }
}

// ---------------- fused projection GEMM (8-phase core) ----------------
// W rows: [0,1024)=Q1 [1024,2048)=K1 [2048,3072)=V1 [3072,4096)=Q2(skipped)
// [4096,5120)=K2 [5120,6144)=V2. A = de_x for Q1, en_x otherwise.
// Q scaled by 0.125; V written transposed: Vt[((b*16+h)*64+dh)][s].
__global__ __launch_bounds__(512, 2) void gemm256_proj_k(const u16* __restrict__ Ade,
        const u16* __restrict__ Aen, const u16* __restrict__ W,
        const float* __restrict__ b1, const float* __restrict__ b2,
        u16* __restrict__ Qb, u16* __restrict__ Kb1, u16* __restrict__ Vt1,
        u16* __restrict__ Kb2, u16* __restrict__ Vt2) {
    const int K = 1024;
    __shared__ u16 As[32768];
    __shared__ u16 Bs[32768];
    const int xt = blockIdx.x;
    const int n0 = (xt < 12 ? xt : xt + 4) * 256;    // skip Q2 segment
    const int seg = n0 >> 10;                        // 0,1,2,4,5
    const int m0 = blockIdx.y * 256;
    const u16* A = (seg == 0) ? Ade : Aen;
    f32x4 acc[8][4] = {};
    g256_core(A + (size_t)m0 * K, W + (size_t)n0 * K, K, As, Bs, acc);

    const int lane = threadIdx.x & 63, wid = threadIdx.x >> 6;
    const int wm = wid >> 2, wn = wid & 3, l15 = lane & 15, l4 = lane >> 4;
    const float* bias = (seg < 3) ? (b1 + seg * 1024) : (b2 + (seg - 3) * 1024);
    const int isV = (seg == 2 || seg == 5);
    u16* Orow = (seg == 0) ? Qb : (seg == 1 ? Kb1 : Kb2);
    u16* Ovt  = (seg == 2) ? Vt1 : Vt2;
    const float scale = (seg == 0) ? 0.125f : 1.0f;

    #pragma unroll
    for (int mf = 0; mf < 8; ++mf)
        #pragma unroll
        for (int nf = 0; nf < 4; ++nf) {
            int colg = n0 + wn * 64 + nf * 16 + l15;
            int col = colg & 1023;
            float bv = bias[col];
            int row0 = m0 + wm * 128 + mf * 16 + l4 * 4;
            if (isV) {
                ushort4 o;
                o.x = f2bf(acc[mf][nf][0] + bv);
                o.y = f2bf(acc[mf][nf][1] + bv);
                o.z = f2bf(acc[mf][nf][2] + bv);
                o.w = f2bf(acc[mf][nf][3] + bv);
                size_t off = ((size_t)((row0 >> 10) * 16 + (col >> 6)) * 64
                              + (col & 63)) * 1024 + (row0 & 1023);
                *(ushort4*)&Ovt[off] = o;
            } else {
                #pragma unroll
                for (int i = 0; i < 4; ++i)
                    Orow[(size_t)(row0 + i) * 1024 + col] =
                        f2bf((acc[mf][nf][i] + bv) * scale);
            }
        }
}

// ---------------- flash attention (unchanged) ----------------
template <int CAUSAL>
__global__ __launch_bounds__(256) void attn_k(const u16* __restrict__ Q,
                                              const u16* __restrict__ Kg_,
                                              const u16* __restrict__ Vt_,
                                              u16* __restrict__ O, int S) {
    const int HD = 1024;
    __shared__ u16 Kl[2][4096];
    __shared__ u16 Vl[2][4096];
    __shared__ u16 Pl[4][16 * 72];
    const int tid = threadIdx.x, lane = tid & 63, w = tid >> 6;
    const int qt = blockIdx.x, h = blockIdx.y, b = blockIdx.z;
    const u16* Qg  = Q   + ((size_t)b * S) * HD + h * 64;
    const u16* Kgp = Kg_ + ((size_t)b * S) * HD + h * 64;
    const u16* Vtp = Vt_ + (size_t)(b * 16 + h) * 64 * 1024;
    const int q0 = qt * 64 + w * 16;
    const int l15 = lane & 15, l4 = lane >> 4;
    const int sr = lane >> 3, sc = lane & 7;

    bf16x8 aq[2];
    #pragma unroll
    for (int kc = 0; kc < 2; ++kc)
        aq[kc] = *(const bf16x8*)&Qg[(size_t)(q0 + l15) * HD + kc * 32 + l4 * 8];

    f32x4 acc_o[4] = {};
    float mrow[4], lrow[4];
    #pragma unroll
    for (int i = 0; i < 4; ++i) { mrow[i] = -3.0e38f; lrow[i] = 0.f; }
    u16* Pw = Pl[w];

    const int nkb = CAUSAL ? (qt + 1) : (S / 64);

    {
        #pragma unroll
        for (int qq = 0; qq < 2; ++qq) {
            int rbase = w * 16 + qq * 8;
            int r = rbase + sr;
            int cs = sc ^ (r & 7);
            gl_lds16(Kgp + (size_t)r * HD + cs * 8, (void*)&Kl[0][rbase * 64]);
            gl_lds16(Vtp + (size_t)r * 1024 + cs * 8, (void*)&Vl[0][rbase * 64]);
        }
    }
    __syncthreads();

    int buf = 0;
    for (int kb = 0; kb < nkb; ++kb) {
        if (kb + 1 < nkb) {
            const int k0n = (kb + 1) * 64;
            #pragma unroll
            for (int qq = 0; qq < 2; ++qq) {
                int rbase = w * 16 + qq * 8;
                int r = rbase + sr;
                int cs = sc ^ (r & 7);
                gl_lds16(Kgp + (size_t)(k0n + r) * HD + cs * 8, (void*)&Kl[buf ^ 1][rbase * 64]);
                gl_lds16(Vtp + (size_t)r * 1024 + k0n + cs * 8, (void*)&Vl[buf ^ 1][rbase * 64]);
            }
        }
        const u16* Kc = Kl[buf];
        const u16* Vc = Vl[buf];

        f32x4 accs[4] = {};
        #pragma unroll
        for (int ct = 0; ct < 4; ++ct) {
            int row = ct * 16 + l15;
            #pragma unroll
            for (int kc = 0; kc < 2; ++kc) {
                int g = kc * 4 + l4;
                bf16x8 bk = *(const bf16x8*)&Kc[row * 64 + (g ^ (row & 7)) * 8];
                accs[ct] = __builtin_amdgcn_mfma_f32_16x16x32_bf16(aq[kc], bk, accs[ct], 0, 0, 0);
            }
        }

        float vals[4][4], tmax[4];
        #pragma unroll
        for (int i = 0; i < 4; ++i) tmax[i] = -3.0e38f;
        if (CAUSAL && kb == qt) {
            #pragma unroll
            for (int ct = 0; ct < 4; ++ct)
                #pragma unroll
                for (int i = 0; i < 4; ++i) {
                    float v = accs[ct][i];
                    int kr = ct * 16 + l15;
                    int qr = w * 16 + l4 * 4 + i;
                    if (kr > qr) v = -1.0e9f;
                    vals[ct][i] = v;
                    tmax[i] = fmaxf(tmax[i], v);
                }
        } else {
            #pragma unroll
            for (int ct = 0; ct < 4; ++ct)
                #pragma unroll
                for (int i = 0; i < 4; ++i) {
                    float v = accs[ct][i];
                    vals[ct][i] = v;
                    tmax[i] = fmaxf(tmax[i], v);
                }
        }
        #pragma unroll
        for (int off = 1; off < 16; off <<= 1)
            #pragma unroll
            for (int i = 0; i < 4; ++i) tmax[i] = fmaxf(tmax[i], __shfl_xor(tmax[i], off));

        float scale[4], rsum[4];
        #pragma unroll
        for (int i = 0; i < 4; ++i) {
            float mn = fmaxf(mrow[i], tmax[i]);
            scale[i] = __expf(mrow[i] - mn);
            mrow[i] = mn;
            rsum[i] = 0.f;
        }
        #pragma unroll
        for (int ct = 0; ct < 4; ++ct)
            #pragma unroll
            for (int i = 0; i < 4; ++i) {
                float p = __expf(vals[ct][i] - mrow[i]);
                vals[ct][i] = p;
                rsum[i] += p;
            }
        #pragma unroll
        for (int off = 1; off < 16; off <<= 1)
            #pragma unroll
            for (int i = 0; i < 4; ++i) rsum[i] += __shfl_xor(rsum[i], off);
        #pragma unroll
        for (int i = 0; i < 4; ++i) lrow[i] = lrow[i] * scale[i] + rsum[i];
        #pragma unroll
        for (int dt = 0; dt < 4; ++dt)
            #pragma unroll
            for (int i = 0; i < 4; ++i) acc_o[dt][i] *= scale[i];

        #pragma unroll
        for (int ct = 0; ct < 4; ++ct)
            #pragma unroll
            for (int i = 0; i < 4; ++i)
                Pw[(l4 * 4 + i) * 72 + ct * 16 + l15] = f2bf(vals[ct][i]);

        #pragma unroll
        for (int kc2 = 0; kc2 < 2; ++kc2) {
            bf16x8 pa = *(const bf16x8*)&Pw[l15 * 72 + kc2 * 32 + l4 * 8];
            #pragma unroll
            for (int dt = 0; dt < 4; ++dt) {
                int row = dt * 16 + l15;
                int g = kc2 * 4 + l4;
                bf16x8 bv = *(const bf16x8*)&Vc[row * 64 + (g ^ (row & 7)) * 8];
                acc_o[dt] = __builtin_amdgcn_mfma_f32_16x16x32_bf16(pa, bv, acc_o[dt], 0, 0, 0);
            }
        }
        __syncthreads();
        buf ^= 1;
    }

    #pragma unroll
    for (int dt = 0; dt < 4; ++dt)
        #pragma unroll
        for (int i = 0; i < 4; ++i) {
            float o = acc_o[dt][i] / lrow[i];
            O[(size_t)(b * S + q0 + l4 * 4 + i) * HD + h * 64 + dt * 16 + l15] = f2bf(o);
        }
}

extern "C" void kernel_launch(void* const* d_in, const int* in_sizes, int n_in,
                              void* d_out, int out_size, void* d_ws, size_t ws_size,
                              hipStream_t stream) {
    const float* de_x = (const float*)d_in[0];
    const float* en_x = (const float*)d_in[1];
    const float* a1w  = (const float*)d_in[3];
    const float* a1b  = (const float*)d_in[4];
    const float* a2w  = (const float*)d_in[5];
    const float* a2b  = (const float*)d_in[6];
    const float* fw1  = (const float*)d_in[7];
    const float* fb1  = (const float*)d_in[8];
    const float* fw2  = (const float*)d_in[9];
    const float* fb2  = (const float*)d_in[10];
    float* out = (float*)d_out;
    u16* ws = (u16*)d_ws;

    // workspace layout (u16 elems), aliases keep total at 138.4 MB
    u16* bf_de = ws + 0;          // 8388608   (later: h2)
    u16* bf_en = ws + 8388608;    // 8388608   (later: h1)
    u16* wproj = ws + 16777216;   // 6291456 = 6 x [1024][1024]
    u16* wf1t  = ws + 23068672;   // 2097152
    u16* wf2t  = ws + 25165824;   // 2097152
    u16* Qb    = ws + 27262976;   // 8388608
    u16* Kb1   = ws + 35651584;   // 8388608   (later: mid, spans Kb1+Vt1)
    u16* Vt1   = ws + 44040192;   // 8388608
    u16* Kb2   = ws + 52428800;   // 8388608
    u16* Vt2   = ws + 60817408;   // 8388608
    u16* h1  = bf_en;
    u16* h2  = bf_de;
    u16* mid = Kb1;               // 16777216 elems
    if (ws_size < (size_t)69206016 * 2) return;

    dim3 blk(256);

    cvt_bf16_k<<<8192, blk, 0, stream>>>(de_x, bf_de, 2097152);
    cvt_bf16_k<<<8192, blk, 0, stream>>>(en_x, bf_en, 2097152);
    pack_attn_w_k<<<12288, blk, 0, stream>>>(a1w, wproj);
    pack_attn_w_k<<<12288, blk, 0, stream>>>(a2w, wproj + 3145728);
    transpose_bf16_k<<<8192, blk, 0, stream>>>(fw1, wf1t, 1024, 2048);
    transpose_bf16_k<<<8192, blk, 0, stream>>>(fw2, wf2t, 2048, 1024);

    // fused projections: Q1,K1,V1,K2,V2 (Q scaled, V transposed)
    gemm256_proj_k<<<dim3(20, 32), 512, 0, stream>>>(bf_de, bf_en, wproj, a1b, a2b,
                                                     Qb, Kb1, Vt1, Kb2, Vt2);
    attn_k<1><<<dim3(16, 16, 8), blk, 0, stream>>>(Qb, Kb1, Vt1, h1, 1024);

    // Q2 = h1 @ Wq2 (scaled)
    gemm256_k<0><<<dim3(4, 32), 512, 0, stream>>>(h1, wproj + 3145728, a2b,
                                                  Qb, nullptr, 8192, 1024, 1024, 0.125f);
    attn_k<0><<<dim3(16, 16, 8), blk, 0, stream>>>(Qb, Kb2, Vt2, h2, 1024);

    // FFN
    gemm256_k<1><<<dim3(8, 32), 512, 0, stream>>>(h2, wf1t, fb1, mid, nullptr,
                                                  8192, 2048, 1024, 1.0f);
    gemm256_k<2><<<dim3(4, 32), 512, 0, stream>>>(mid, wf2t, fb2, nullptr, out,
                                                  8192, 1024, 2048, 1.0f);
}

// Round 9
// 608.623 us; speedup vs baseline: 1.3766x; 1.1507x over previous
//
#include <hip/hip_runtime.h>

typedef unsigned short u16;
typedef __attribute__((ext_vector_type(8))) __bf16 bf16x8;
typedef __attribute__((ext_vector_type(4))) float f32x4;

__device__ __forceinline__ u16 f2bf(float f) {
    unsigned int u = __builtin_bit_cast(unsigned int, f);
    u = (u + 0x7fffu + ((u >> 16) & 1u)) >> 16;
    return (u16)u;
}

typedef __attribute__((address_space(1))) const void gv_t;
typedef __attribute__((address_space(3))) void lv_t;
__device__ __forceinline__ void gl_lds16(const void* g, void* l) {
    __builtin_amdgcn_global_load_lds((gv_t*)g, (lv_t*)l, 16, 0, 0);
}

// ---------------- convert fp32 -> bf16 (vectorized x4) ----------------
__global__ __launch_bounds__(256) void cvt_bf16_k(const float* __restrict__ in,
                                                  u16* __restrict__ out, int n4) {
    int i = blockIdx.x * 256 + threadIdx.x;
    if (i >= n4) return;
    float4 f = ((const float4*)in)[i];
    ushort4 o;
    o.x = f2bf(f.x); o.y = f2bf(f.y); o.z = f2bf(f.z); o.w = f2bf(f.w);
    ((ushort4*)out)[i] = o;
}

// ---- tiled transpose fp32 [R][C] -> bf16 [C][R], coalesced both sides ----
// grid (C/32, R/32, n_slabs); slab = contiguous [R][C] block of in AND out.
__global__ __launch_bounds__(256) void transpose_pack_k(const float* __restrict__ in,
                                                        u16* __restrict__ out,
                                                        int R, int C) {
    __shared__ float t[32][33];
    const size_t slab = (size_t)blockIdx.z * R * C;
    in  += slab;
    out += slab;
    const int c0 = blockIdx.x * 32, r0 = blockIdx.y * 32;
    const int tx = threadIdx.x & 31, ty = threadIdx.x >> 5;   // 32x8
    #pragma unroll
    for (int j = 0; j < 32; j += 8)
        t[ty + j][tx] = in[(size_t)(r0 + ty + j) * C + c0 + tx];
    __syncthreads();
    #pragma unroll
    for (int j = 0; j < 32; j += 8)
        out[(size_t)(c0 + ty + j) * R + r0 + tx] = f2bf(t[tx][ty + j]);
}

// ================= 256x256 8-phase GEMM core v2 (T2+T3+T4+T5) =================
// (unchanged from round 6 — ledger desk-verified 3x; see comments)
__device__ __forceinline__ void g256_core(const u16* __restrict__ Ab,
                                          const u16* __restrict__ Bb,
                                          int K, u16* __restrict__ As,
                                          u16* __restrict__ Bs,
                                          f32x4 (&acc)[8][4]) {
    const int tid = threadIdx.x, lane = tid & 63, wid = tid >> 6;
    const int wm = wid >> 2, wn = wid & 3;
    const int l15 = lane & 15, l4 = lane >> 4;
    const int gsw = (lane & 7) ^ ((lane >> 3) & 7);  // inverse-swizzled src granule
    const int lr = lane >> 3;

    bf16x8 a[4][2], b[4][2];

#define STG(MATb, MATs, buf, half, kt) { \
    _Pragma("unroll") \
    for (int j = 0; j < 2; ++j) { \
        const int r = (half) * 128 + j * 64 + wid * 8; \
        gl_lds16(MATb + (size_t)(r + lr) * K + (kt) * 64 + gsw * 8, \
                 &MATs[(buf) * 16384 + r * 64]); \
    } }
#define LDA(buf, MLO) { \
    _Pragma("unroll") \
    for (int mf = 0; mf < 4; ++mf) \
    _Pragma("unroll") \
    for (int ks = 0; ks < 2; ++ks) \
        a[mf][ks] = *(const bf16x8*)&As[(buf) * 16384 \
            + (wm * 128 + ((MLO) + mf) * 16 + l15) * 64 \
            + (((ks * 4 + l4) ^ (l15 & 7)) * 8)]; \
    }
#define LDB(buf, NLO) { \
    _Pragma("unroll") \
    for (int nf = 0; nf < 2; ++nf) \
    _Pragma("unroll") \
    for (int ks = 0; ks < 2; ++ks) \
        b[(NLO) + nf][ks] = *(const bf16x8*)&Bs[(buf) * 16384 \
            + (wn * 64 + ((NLO) + nf) * 16 + l15) * 64 \
            + (((ks * 4 + l4) ^ (l15 & 7)) * 8)]; \
    }
#define MMA(MLO, NLO) { \
    __builtin_amdgcn_s_setprio(1); \
    _Pragma("unroll") \
    for (int mf = 0; mf < 4; ++mf) \
    _Pragma("unroll") \
    for (int nf = 0; nf < 2; ++nf) \
    _Pragma("unroll") \
    for (int ks = 0; ks < 2; ++ks) \
        acc[(MLO) + mf][(NLO) + nf] = __builtin_amdgcn_mfma_f32_16x16x32_bf16( \
            a[mf][ks], b[(NLO) + nf][ks], acc[(MLO) + mf][(NLO) + nf], 0, 0, 0); \
    __builtin_amdgcn_s_setprio(0); \
    }
#define BARR __builtin_amdgcn_s_barrier()
#define LGKM0 { asm volatile("s_waitcnt lgkmcnt(0)" ::: "memory"); \
                __builtin_amdgcn_sched_barrier(0); }
#define WTV6 asm volatile("s_waitcnt vmcnt(6)" ::: "memory")
#define WTV8 asm volatile("s_waitcnt vmcnt(8)" ::: "memory")
#define WTV0 asm volatile("s_waitcnt vmcnt(0)" ::: "memory")

    const int NI = K >> 7;
    STG(Ab, As, 0, 0, 0); STG(Ab, As, 0, 1, 0);
    STG(Bb, Bs, 0, 0, 0); STG(Bb, Bs, 0, 1, 0);
    STG(Ab, As, 1, 0, 1); STG(Ab, As, 1, 1, 1);
    STG(Bb, Bs, 1, 0, 1); STG(Bb, Bs, 1, 1, 1);
    WTV8;
    BARR;

    for (int it = 0; it < NI; ++it) {
        const int t2 = 2 * it + 2, t3 = 2 * it + 3;
        const bool nl = (it + 1 < NI);
        // ph0
        LDA(0, 0); LDB(0, 0);
        BARR; LGKM0; MMA(0, 0); BARR;
        // ph1
        LDB(0, 2);
        BARR; LGKM0; MMA(0, 2); BARR;
        // ph2  (B-buf0 free since ph1)
        LDA(0, 4);
        if (nl) STG(Bb, Bs, 0, 0, t2);
        BARR; LGKM0; MMA(4, 2); BARR;
        // ph3  (A-buf0 free since ph2; read-free)
        if (nl) { STG(Ab, As, 0, 0, t2); STG(Bb, Bs, 0, 1, t2); }
        BARR; MMA(4, 0);
        if (nl) { WTV6; } else { WTV0; }
        BARR;
        // ph4
        LDA(1, 0); LDB(1, 0);
        if (nl) STG(Ab, As, 0, 1, t2);
        BARR; LGKM0; MMA(0, 0); BARR;
        // ph5
        LDB(1, 2);
        BARR; LGKM0; MMA(0, 2); BARR;
        // ph6  (B-buf1 free since ph5)
        LDA(1, 4);
        if (nl) STG(Bb, Bs, 1, 0, t3);
        BARR; LGKM0; MMA(4, 2); BARR;
        // ph7  (A-buf1 free since ph6; read-free)
        if (nl) { STG(Ab, As, 1, 0, t3); STG(Ab, As, 1, 1, t3); STG(Bb, Bs, 1, 1, t3); }
        BARR; MMA(4, 0);
        if (nl) WTV8;
        BARR;
    }
#undef STG
#undef LDA
#undef LDB
#undef MMA
#undef BARR
#undef LGKM0
#undef WTV6
#undef WTV8
#undef WTV0
}

// ---------------- generic 256x256 GEMM: C = (A @ Bt^T + bias)[relu]*scale ----
template <int MODE>
__global__ __launch_bounds__(512, 2) void gemm256_k(const u16* __restrict__ A,
        const u16* __restrict__ Bt, const float* __restrict__ bias,
        u16* __restrict__ Obf, float* __restrict__ Of,
        int M, int N, int K, float scale) {
    __shared__ u16 As[32768];
    __shared__ u16 Bs[32768];
    const int m0 = blockIdx.y * 256, n0 = blockIdx.x * 256;
    f32x4 acc[8][4] = {};
    g256_core(A + (size_t)m0 * K, Bt + (size_t)n0 * K, K, As, Bs, acc);

    const int lane = threadIdx.x & 63, wid = threadIdx.x >> 6;
    const int wm = wid >> 2, wn = wid & 3, l15 = lane & 15, l4 = lane >> 4;
    #pragma unroll
    for (int mf = 0; mf < 8; ++mf)
        #pragma unroll
        for (int nf = 0; nf < 4; ++nf) {
            int col = n0 + wn * 64 + nf * 16 + l15;
            float bv = bias[col];
            int row0 = m0 + wm * 128 + mf * 16 + l4 * 4;
            #pragma unroll
            for (int i = 0; i < 4; ++i) {
                float v = acc[mf][nf][i] + bv;
                if (MODE == 1) v = fmaxf(v, 0.f);
                v *= scale;
                if (MODE == 2) Of[(size_t)(row0 + i) * N + col] = v;
                else           Obf[(size_t)(row0 + i) * N + col] = f2bf(v);
            }
        }
}

// ---------------- fused projection GEMM (8-phase core v2) ----------------
__global__ __launch_bounds__(512, 2) void gemm256_proj_k(const u16* __restrict__ Ade,
        const u16* __restrict__ Aen, const u16* __restrict__ W,
        const float* __restrict__ b1, const float* __restrict__ b2,
        u16* __restrict__ Qb, u16* __restrict__ Kb1, u16* __restrict__ Vt1,
        u16* __restrict__ Kb2, u16* __restrict__ Vt2) {
    const int K = 1024;
    __shared__ u16 As[32768];
    __shared__ u16 Bs[32768];
    const int xt = blockIdx.x;
    const int n0 = (xt < 12 ? xt : xt + 4) * 256;    // skip Q2 segment
    const int seg = n0 >> 10;                        // 0,1,2,4,5
    const int m0 = blockIdx.y * 256;
    const u16* A = (seg == 0) ? Ade : Aen;
    f32x4 acc[8][4] = {};
    g256_core(A + (size_t)m0 * K, W + (size_t)n0 * K, K, As, Bs, acc);

    const int lane = threadIdx.x & 63, wid = threadIdx.x >> 6;
    const int wm = wid >> 2, wn = wid & 3, l15 = lane & 15, l4 = lane >> 4;
    const float* bias = (seg < 3) ? (b1 + seg * 1024) : (b2 + (seg - 3) * 1024);
    const int isV = (seg == 2 || seg == 5);
    u16* Orow = (seg == 0) ? Qb : (seg == 1 ? Kb1 : Kb2);
    u16* Ovt  = (seg == 2) ? Vt1 : Vt2;
    const float scale = (seg == 0) ? 0.125f : 1.0f;

    #pragma unroll
    for (int mf = 0; mf < 8; ++mf)
        #pragma unroll
        for (int nf = 0; nf < 4; ++nf) {
            int colg = n0 + wn * 64 + nf * 16 + l15;
            int col = colg & 1023;
            float bv = bias[col];
            int row0 = m0 + wm * 128 + mf * 16 + l4 * 4;
            if (isV) {
                ushort4 o;
                o.x = f2bf(acc[mf][nf][0] + bv);
                o.y = f2bf(acc[mf][nf][1] + bv);
                o.z = f2bf(acc[mf][nf][2] + bv);
                o.w = f2bf(acc[mf][nf][3] + bv);
                size_t off = ((size_t)((row0 >> 10) * 16 + (col >> 6)) * 64
                              + (col & 63)) * 1024 + (row0 & 1023);
                *(ushort4*)&Ovt[off] = o;
            } else {
                #pragma unroll
                for (int i = 0; i < 4; ++i)
                    Orow[(size_t)(row0 + i) * 1024 + col] =
                        f2bf((acc[mf][nf][i] + bv) * scale);
            }
        }
}

// ---------------- flash attention v2: 128 q-rows/block, 8 waves ----------------
// Q pre-scaled by 1/8. K: [B,S,HD]. Vt: [(b*16+h)*64+dh][S].
// 512 threads = 8 waves x 16 q-rows. KBLK=64, double-buffered K/Vt in LDS
// (XOR chunk swizzle, global_load_lds linear dest / pre-swizzled source).
// LDS 50KB -> 3 blocks/CU = 24 waves/CU. Causal: mask via global-index
// compare when kb >= 2*qt; nkb = 2qt+2.
template <int CAUSAL>
__global__ __launch_bounds__(512) void attn_k(const u16* __restrict__ Q,
                                              const u16* __restrict__ Kg_,
                                              const u16* __restrict__ Vt_,
                                              u16* __restrict__ O, int S) {
    const int HD = 1024;
    __shared__ u16 Kl[2][4096];
    __shared__ u16 Vl[2][4096];
    __shared__ u16 Pl[8][16 * 72];
    const int tid = threadIdx.x, lane = tid & 63, w = tid >> 6;   // w in 0..7
    const int qt = blockIdx.x, h = blockIdx.y, b = blockIdx.z;
    const u16* Qg  = Q   + ((size_t)b * S) * HD + h * 64;
    const u16* Kgp = Kg_ + ((size_t)b * S) * HD + h * 64;
    const u16* Vtp = Vt_ + (size_t)(b * 16 + h) * 64 * 1024;
    const int q0 = qt * 128 + w * 16;
    const int l15 = lane & 15, l4 = lane >> 4;
    const int sr = lane >> 3, sc = lane & 7;      // staging: row-in-8 / chunk
    const int rbase = w * 8;                      // this wave stages rows rbase..rbase+7
    const int r = rbase + sr;
    const int cs = sc ^ (r & 7);

    bf16x8 aq[2];
    #pragma unroll
    for (int kc = 0; kc < 2; ++kc)
        aq[kc] = *(const bf16x8*)&Qg[(size_t)(q0 + l15) * HD + kc * 32 + l4 * 8];

    f32x4 acc_o[4] = {};
    float mrow[4], lrow[4];
    #pragma unroll
    for (int i = 0; i < 4; ++i) { mrow[i] = -3.0e38f; lrow[i] = 0.f; }
    u16* Pw = Pl[w];

    const int nkb = CAUSAL ? (2 * qt + 2) : (S / 64);

    // prologue: stage tile 0 into buf 0 (1 K-load + 1 V-load per thread)
    gl_lds16(Kgp + (size_t)r * HD + cs * 8, (void*)&Kl[0][rbase * 64]);
    gl_lds16(Vtp + (size_t)r * 1024 + cs * 8, (void*)&Vl[0][rbase * 64]);
    __syncthreads();

    int buf = 0;
    for (int kb = 0; kb < nkb; ++kb) {
        if (kb + 1 < nkb) {
            const int k0n = (kb + 1) * 64;
            gl_lds16(Kgp + (size_t)(k0n + r) * HD + cs * 8, (void*)&Kl[buf ^ 1][rbase * 64]);
            gl_lds16(Vtp + (size_t)r * 1024 + k0n + cs * 8, (void*)&Vl[buf ^ 1][rbase * 64]);
        }
        const u16* Kc = Kl[buf];
        const u16* Vc = Vl[buf];

        // QK^T: scores [16 q][64 k] per wave (Q pre-scaled)
        f32x4 accs[4] = {};
        #pragma unroll
        for (int ct = 0; ct < 4; ++ct) {
            int row = ct * 16 + l15;
            #pragma unroll
            for (int kc = 0; kc < 2; ++kc) {
                int g = kc * 4 + l4;
                bf16x8 bk = *(const bf16x8*)&Kc[row * 64 + (g ^ (row & 7)) * 8];
                accs[ct] = __builtin_amdgcn_mfma_f32_16x16x32_bf16(aq[kc], bk, accs[ct], 0, 0, 0);
            }
        }

        float vals[4][4], tmax[4];
        #pragma unroll
        for (int i = 0; i < 4; ++i) tmax[i] = -3.0e38f;
        if (CAUSAL && kb >= 2 * qt) {
            #pragma unroll
            for (int ct = 0; ct < 4; ++ct)
                #pragma unroll
                for (int i = 0; i < 4; ++i) {
                    float v = accs[ct][i];
                    int kg = kb * 64 + ct * 16 + l15;   // global key index
                    int qg = q0 + l4 * 4 + i;           // global query index
                    if (kg > qg) v = -1.0e9f;
                    vals[ct][i] = v;
                    tmax[i] = fmaxf(tmax[i], v);
                }
        } else {
            #pragma unroll
            for (int ct = 0; ct < 4; ++ct)
                #pragma unroll
                for (int i = 0; i < 4; ++i) {
                    float v = accs[ct][i];
                    vals[ct][i] = v;
                    tmax[i] = fmaxf(tmax[i], v);
                }
        }
        #pragma unroll
        for (int off = 1; off < 16; off <<= 1)
            #pragma unroll
            for (int i = 0; i < 4; ++i) tmax[i] = fmaxf(tmax[i], __shfl_xor(tmax[i], off));

        float scale[4], rsum[4];
        #pragma unroll
        for (int i = 0; i < 4; ++i) {
            float mn = fmaxf(mrow[i], tmax[i]);
            scale[i] = __expf(mrow[i] - mn);
            mrow[i] = mn;
            rsum[i] = 0.f;
        }
        #pragma unroll
        for (int ct = 0; ct < 4; ++ct)
            #pragma unroll
            for (int i = 0; i < 4; ++i) {
                float p = __expf(vals[ct][i] - mrow[i]);
                vals[ct][i] = p;
                rsum[i] += p;
            }
        #pragma unroll
        for (int off = 1; off < 16; off <<= 1)
            #pragma unroll
            for (int i = 0; i < 4; ++i) rsum[i] += __shfl_xor(rsum[i], off);
        #pragma unroll
        for (int i = 0; i < 4; ++i) lrow[i] = lrow[i] * scale[i] + rsum[i];
        #pragma unroll
        for (int dt = 0; dt < 4; ++dt)
            #pragma unroll
            for (int i = 0; i < 4; ++i) acc_o[dt][i] *= scale[i];

        // P -> LDS (bf16), then PV
        #pragma unroll
        for (int ct = 0; ct < 4; ++ct)
            #pragma unroll
            for (int i = 0; i < 4; ++i)
                Pw[(l4 * 4 + i) * 72 + ct * 16 + l15] = f2bf(vals[ct][i]);

        #pragma unroll
        for (int kc2 = 0; kc2 < 2; ++kc2) {
            bf16x8 pa = *(const bf16x8*)&Pw[l15 * 72 + kc2 * 32 + l4 * 8];
            #pragma unroll
            for (int dt = 0; dt < 4; ++dt) {
                int row = dt * 16 + l15;                // dh
                int g = kc2 * 4 + l4;
                bf16x8 bv = *(const bf16x8*)&Vc[row * 64 + (g ^ (row & 7)) * 8];
                acc_o[dt] = __builtin_amdgcn_mfma_f32_16x16x32_bf16(pa, bv, acc_o[dt], 0, 0, 0);
            }
        }
        __syncthreads();
        buf ^= 1;
    }

    #pragma unroll
    for (int dt = 0; dt < 4; ++dt)
        #pragma unroll
        for (int i = 0; i < 4; ++i) {
            float o = acc_o[dt][i] / lrow[i];
            O[(size_t)(b * S + q0 + l4 * 4 + i) * HD + h * 64 + dt * 16 + l15] = f2bf(o);
        }
}

extern "C" void kernel_launch(void* const* d_in, const int* in_sizes, int n_in,
                              void* d_out, int out_size, void* d_ws, size_t ws_size,
                              hipStream_t stream) {
    const float* de_x = (const float*)d_in[0];
    const float* en_x = (const float*)d_in[1];
    const float* a1w  = (const float*)d_in[3];
    const float* a1b  = (const float*)d_in[4];
    const float* a2w  = (const float*)d_in[5];
    const float* a2b  = (const float*)d_in[6];
    const float* fw1  = (const float*)d_in[7];
    const float* fb1  = (const float*)d_in[8];
    const float* fw2  = (const float*)d_in[9];
    const float* fb2  = (const float*)d_in[10];
    float* out = (float*)d_out;
    u16* ws = (u16*)d_ws;

    // workspace layout (u16 elems), aliases keep total at 138.4 MB
    u16* bf_de = ws + 0;          // 8388608   (later: h2)
    u16* bf_en = ws + 8388608;    // 8388608   (later: h1)
    u16* wproj = ws + 16777216;   // 6291456 = 6 x [1024][1024]
    u16* wf1t  = ws + 23068672;   // 2097152
    u16* wf2t  = ws + 25165824;   // 2097152
    u16* Qb    = ws + 27262976;   // 8388608
    u16* Kb1   = ws + 35651584;   // 8388608   (later: mid, spans Kb1+Vt1)
    u16* Vt1   = ws + 44040192;   // 8388608
    u16* Kb2   = ws + 52428800;   // 8388608
    u16* Vt2   = ws + 60817408;   // 8388608
    u16* h1  = bf_en;
    u16* h2  = bf_de;
    u16* mid = Kb1;               // 16777216 elems
    if (ws_size < (size_t)69206016 * 2) return;

    dim3 blk(256);

    cvt_bf16_k<<<8192, blk, 0, stream>>>(de_x, bf_de, 2097152);
    cvt_bf16_k<<<8192, blk, 0, stream>>>(en_x, bf_en, 2097152);
    // attn weights: 48 slabs (= 3 proj x 16 heads) of [1024 d][64 kk] -> [64][1024]
    transpose_pack_k<<<dim3(2, 32, 48), blk, 0, stream>>>(a1w, wproj, 1024, 64);
    transpose_pack_k<<<dim3(2, 32, 48), blk, 0, stream>>>(a2w, wproj + 3145728, 1024, 64);
    transpose_pack_k<<<dim3(64, 32, 1), blk, 0, stream>>>(fw1, wf1t, 1024, 2048);
    transpose_pack_k<<<dim3(32, 64, 1), blk, 0, stream>>>(fw2, wf2t, 2048, 1024);

    // fused projections: Q1,K1,V1,K2,V2 (Q scaled, V transposed)
    gemm256_proj_k<<<dim3(20, 32), 512, 0, stream>>>(bf_de, bf_en, wproj, a1b, a2b,
                                                     Qb, Kb1, Vt1, Kb2, Vt2);
    attn_k<1><<<dim3(8, 16, 8), 512, 0, stream>>>(Qb, Kb1, Vt1, h1, 1024);

    // Q2 = h1 @ Wq2 (scaled)
    gemm256_k<0><<<dim3(4, 32), 512, 0, stream>>>(h1, wproj + 3145728, a2b,
                                                  Qb, nullptr, 8192, 1024, 1024, 0.125f);
    attn_k<0><<<dim3(8, 16, 8), 512, 0, stream>>>(Qb, Kb2, Vt2, h2, 1024);

    // FFN
    gemm256_k<1><<<dim3(8, 32), 512, 0, stream>>>(h2, wf1t, fb1, mid, nullptr,
                                                  8192, 2048, 1024, 1.0f);
    gemm256_k<2><<<dim3(4, 32), 512, 0, stream>>>(mid, wf2t, fb2, nullptr, out,
                                                  8192, 1024, 2048, 1.0f);
}